// Round 4
// baseline (1259.708 us; speedup 1.0000x reference)
//
#include <hip/hip_runtime.h>
#include <hip/hip_bf16.h>
#include <math.h>

// ============================================================================
// Block-cooperative bf16 hi/lo split-MFMA evaluator.
// 64 points per 256-thread block (4 waves, wave w gathers point-group pg=w).
// Per MLP m (4 total: opac/cols/cov/motion):
//   layer1: wave w computes hidden rows [32w..32w+32) for ALL 64 points
//           (weights loaded once per block), writes relu'd h to LDS pre-split
//           as bf16 hi/lo arrays.
//   layer2: waves split (nt, point-half) units; B-fragments are direct
//           ds_read_b128 from the split h arrays (no unpack VALU).
// Weight fragments pre-swizzled into d_ws by prep_weights (same layout as r2).
// 3-pass split MFMA: Wh*Bh + Wh*Bl + Wl*Bh  (~1e-5 rel err vs fp32).
// C/D mapping (HW-verified m89): D[row=(lane>>4)*4+reg][col=lane&15].
// A/B built with the same slot->k map => invariant to HW intra-k order.
// Layer-1 bias baked into padded k=63 (feature slot == 1.0).
// ============================================================================

typedef __attribute__((ext_vector_type(8))) short bf16x8;
typedef __attribute__((ext_vector_type(4))) float f32x4;

#define MFMA16(A, B, C) __builtin_amdgcn_mfma_f32_16x16x32_bf16((A), (B), (C), 0, 0, 0)

#define FSTR 104   // feature LDS row stride (bf16): 96 slots + pad, 208 B (16-mult)
#define HSTR 136   // hidden  LDS row stride (bf16): 128 + pad, 272 B (16-mult)

__device__ __forceinline__ unsigned short f2bf(float x) {
    unsigned int u = __float_as_uint(x);          // RNE bf16 (finite inputs)
    u += 0x7FFFu + ((u >> 16) & 1u);
    return (unsigned short)(u >> 16);
}
__device__ __forceinline__ float bf2f(unsigned short h) {
    return __uint_as_float(((unsigned int)h) << 16);
}
__device__ __forceinline__ float sigf(float x) { return 1.0f / (1.0f + __expf(-x)); }

// split 8 f32 -> hi/lo bf16x8 and store to LDS (16B aligned)
__device__ __forceinline__ void split_store(const float* v, short* ph, short* pl) {
    bf16x8 vh, vl;
#pragma unroll
    for (int j = 0; j < 8; ++j) {
        const unsigned short h = f2bf(v[j]);
        vh[j] = (short)h;
        vl[j] = (short)f2bf(v[j] - bf2f(h));
    }
    *reinterpret_cast<bf16x8*>(ph) = vh;
    *reinterpret_cast<bf16x8*>(pl) = vl;
}

// ---------------------------------------------------------------------------
// prep_weights: one 64-thread block per 16x32 MFMA tile (UNCHANGED from r2).
// ws tile layout: tile*2048 + lane*16 -> 8 bf16 hi ; +1024 -> 8 bf16 lo.
// Tiles 0..63:   layer1, mlp m=t>>4, sub=t&15: mt=sub>>1, ks=sub&1.
//                A[hid][k]=w1[k*128+hid]; k==63 -> b1[hid]; k>=IN -> 0.
// Tiles 64..107: layer2 [opac 4 | cols 8 | cov 20 | mot 12], [mt][ks 0..3].
//                A[o][k]=w2[k*O+o]; o>=O -> 0.
// ---------------------------------------------------------------------------
__global__ void __launch_bounds__(64)
prep_weights(const float* __restrict__ ow1, const float* __restrict__ cw1,
             const float* __restrict__ vw1, const float* __restrict__ mw1,
             const float* __restrict__ ob1, const float* __restrict__ cb1,
             const float* __restrict__ vb1, const float* __restrict__ mb1,
             const float* __restrict__ ow2, const float* __restrict__ cw2,
             const float* __restrict__ vw2, const float* __restrict__ mw2,
             char* __restrict__ ws)
{
    const int t = blockIdx.x;
    const int l = threadIdx.x;
    const int g = l >> 4, c = l & 15;
    float vals[8];
    if (t < 64) {
        const int m = t >> 4, s = t & 15, mt = s >> 1, ks = s & 1;
        const float* w1 = (m == 0) ? ow1 : (m == 1) ? cw1 : (m == 2) ? vw1 : mw1;
        const float* b1 = (m == 0) ? ob1 : (m == 1) ? cb1 : (m == 2) ? vb1 : mb1;
        const int IN = (m == 3) ? 56 : 51;
        const int hid = mt * 16 + c;
#pragma unroll
        for (int j = 0; j < 8; ++j) {
            const int k = ks * 32 + g * 8 + j;
            float v = 0.0f;
            if (k < IN)       v = w1[k * 128 + hid];
            else if (k == 63) v = b1[hid];
            vals[j] = v;
        }
    } else {
        const int t2 = t - 64;
        const float* w2; int O, mt, ks;
        if (t2 < 4)       { w2 = ow2; O = 10; mt = 0;            ks = t2; }
        else if (t2 < 12) { w2 = cw2; O = 30; const int u = t2 - 4;  mt = u >> 2; ks = u & 3; }
        else if (t2 < 32) { w2 = vw2; O = 70; const int u = t2 - 12; mt = u >> 2; ks = u & 3; }
        else              { w2 = mw2; O = 37; const int u = t2 - 32; mt = u >> 2; ks = u & 3; }
        const int o = mt * 16 + c;
#pragma unroll
        for (int j = 0; j < 8; ++j) {
            const int k = ks * 32 + g * 8 + j;
            vals[j] = (o < O) ? w2[k * O + o] : 0.0f;
        }
    }
    unsigned int dh[4], dl[4];
#pragma unroll
    for (int d = 0; d < 4; ++d) {
        const unsigned short h0 = f2bf(vals[2 * d]);
        const unsigned short h1 = f2bf(vals[2 * d + 1]);
        const unsigned short l0 = f2bf(vals[2 * d] - bf2f(h0));
        const unsigned short l1 = f2bf(vals[2 * d + 1] - bf2f(h1));
        dh[d] = (unsigned int)h0 | ((unsigned int)h1 << 16);
        dl[d] = (unsigned int)l0 | ((unsigned int)l1 << 16);
    }
    *reinterpret_cast<uint4*>(ws + (size_t)t * 2048 + l * 16)        = make_uint4(dh[0], dh[1], dh[2], dh[3]);
    *reinterpret_cast<uint4*>(ws + (size_t)t * 2048 + 1024 + l * 16) = make_uint4(dl[0], dl[1], dl[2], dl[3]);
}

__device__ __forceinline__ void ldw(const char* __restrict__ ws, int tile, int lane,
                                    bf16x8& wh, bf16x8& wl)
{
    const char* p = ws + (size_t)tile * 2048 + lane * 16;
    wh = *reinterpret_cast<const bf16x8*>(p);
    wl = *reinterpret_cast<const bf16x8*>(p + 1024);
}

__global__ void __launch_bounds__(256, 2)
gif_mfma_kernel(const float* __restrict__ af, const float* __restrict__ anchors,
                const float* __restrict__ scales, const float* __restrict__ tfp_,
                const float* __restrict__ factors, const float* __restrict__ c2w,
                const float* __restrict__ tvalp, const int* __restrict__ vis,
                const float* __restrict__ ob2, const float* __restrict__ cb2,
                const float* __restrict__ vb2, const float* __restrict__ mb2,
                const char* __restrict__ ws, float* __restrict__ out, int M)
{
    // LDS: pre-split bf16 hi/lo for features (96 k-slots/pt) and hidden (128/pt)
    __shared__ __align__(16) short feat_h[64 * FSTR], feat_l[64 * FSTR];
    __shared__ __align__(16) short hb_h[64 * HSTR],  hb_l[64 * HSTR];
    __shared__ float pfbuf[64], mfbuf[64];

    const int tid = threadIdx.x;
    const int w = tid >> 6, lane = tid & 63;
    const int c = lane & 15, g = lane >> 4;

    const int ptl_own = w * 16 + c;                  // own point (gather phase)
    const int pt_own = blockIdx.x * 64 + ptl_own;
    const bool vown = pt_own < M;
    const int idx = vis[vown ? pt_own : (M - 1)];

    const float tval = tvalp[0];
    const int fs = (int)floorf(tval * 29.0f);        // GOP-1
    const float cx = c2w[3], cy = c2w[7], cz = c2w[11];

    // =============== gather: build split features for own pg ===============
    // k-slot map per point: [0..31]=af | [32..63]=feat tail (vd,tfeat,0,bias)
    //                       [64..95]=feat_ tail (tfeat,emb,0,bias)
    {
        float v8[8];
        const float4* a4 = reinterpret_cast<const float4*>(af + (size_t)idx * 32 + g * 8);
        const float4 a0 = a4[0], a1 = a4[1];
        v8[0] = a0.x; v8[1] = a0.y; v8[2] = a0.z; v8[3] = a0.w;
        v8[4] = a1.x; v8[5] = a1.y; v8[6] = a1.z; v8[7] = a1.w;
        split_store(v8, &feat_h[ptl_own * FSTR + g * 8], &feat_l[ptl_own * FSTR + g * 8]);
    }

    float tff, mfac, fa2v, pf;
    {
        const float4 fv = *reinterpret_cast<const float4*>(factors + (size_t)idx * 4);
        tff = sigf(fv.x); mfac = sigf(fv.y); fa2v = sigf(fv.z); pf = sigf(fv.w);
    }
    if (g == 0) { pfbuf[ptl_own] = pf; mfbuf[ptl_own] = mfac; }

    {
        // feat  k=32+u: u<3 -> vd | u in [3,19) -> tfeat[u-3] | 0 | k=63 -> 1
        // feat_ k=32+u: u<16 -> tfeat[u] | u in [16,24) -> emb | 0 | k=63 -> 1
        float fB[8]  = {0, 0, 0, 0, 0, 0, 0, 0};
        float fB_[8] = {0, 0, 0, 0, 0, 0, 0, 0};
        const float* tfp = tfp_ + (size_t)idx * 480 + (size_t)fs * 16;
        if (g == 0) {
            const float ax = anchors[(size_t)idx * 3 + 0];
            const float ay = anchors[(size_t)idx * 3 + 1];
            const float az = anchors[(size_t)idx * 3 + 2];
            const float dx = ax - cx, dy = ay - cy, dz = az - cz;
            const float inv = 1.0f / fmaxf(sqrtf(dx * dx + dy * dy + dz * dz), 1e-8f);
            const float4 t0 = *reinterpret_cast<const float4*>(tfp);
            const float4 t1 = *reinterpret_cast<const float4*>(tfp + 4);
            fB[0] = dx * inv;   fB[1] = dy * inv;   fB[2] = dz * inv;
            fB[3] = t0.x * tff; fB[4] = t0.y * tff; fB[5] = t0.z * tff;
            fB[6] = t0.w * tff; fB[7] = t1.x * tff;
            fB_[0] = t0.x * tff; fB_[1] = t0.y * tff; fB_[2] = t0.z * tff; fB_[3] = t0.w * tff;
            fB_[4] = t1.x * tff; fB_[5] = t1.y * tff; fB_[6] = t1.z * tff; fB_[7] = t1.w * tff;
        } else if (g == 1) {
            const float4 t1 = *reinterpret_cast<const float4*>(tfp + 4);
            const float4 t2 = *reinterpret_cast<const float4*>(tfp + 8);
            const float4 t3 = *reinterpret_cast<const float4*>(tfp + 12);
            fB[0] = t1.y * tff; fB[1] = t1.z * tff; fB[2] = t1.w * tff; fB[3] = t2.x * tff;
            fB[4] = t2.y * tff; fB[5] = t2.z * tff; fB[6] = t2.w * tff; fB[7] = t3.x * tff;
            fB_[0] = t2.x * tff; fB_[1] = t2.y * tff; fB_[2] = t2.z * tff; fB_[3] = t2.w * tff;
            fB_[4] = t3.x * tff; fB_[5] = t3.y * tff; fB_[6] = t3.z * tff; fB_[7] = t3.w * tff;
        } else if (g == 2) {
            const float4 t3 = *reinterpret_cast<const float4*>(tfp + 12);
            fB[0] = t3.y * tff; fB[1] = t3.z * tff; fB[2] = t3.w * tff;
            const float PI = 3.14159265358979323846f;
#pragma unroll
            for (int h = 0; h < 4; ++h) {
                const float fr = (float)(1 << h) * PI * tval;
                fB_[h]     = sinf(fr);
                fB_[4 + h] = cosf(fr);
            }
        } else {
            fB[7]  = 1.0f;   // bias slot k=63
            fB_[7] = 1.0f;
        }
        split_store(fB,  &feat_h[ptl_own * FSTR + 32 + g * 8], &feat_l[ptl_own * FSTR + 32 + g * 8]);
        split_store(fB_, &feat_h[ptl_own * FSTR + 64 + g * 8], &feat_l[ptl_own * FSTR + 64 + g * 8]);
    }

    // ---- tail outputs for own point: sc'(6)@147 | fa(4)@153 | an(3)@157 ----
    if (vown) {
        float* outrow = out + (size_t)pt_own * 160;
        if (g == 0) {
            const float* sp = scales + (size_t)idx * 6;
#pragma unroll
            for (int i = 0; i < 6; ++i) {
                float s = __expf(sp[i]);
                if (i >= 3) s *= pf;
                outrow[147 + i] = s;
            }
        } else if (g == 1) {
            outrow[153] = tff; outrow[154] = mfac; outrow[155] = fa2v; outrow[156] = pf;
        } else if (g == 2) {
            outrow[157] = anchors[(size_t)idx * 3 + 0];
            outrow[158] = anchors[(size_t)idx * 3 + 1];
            outrow[159] = anchors[(size_t)idx * 3 + 2];
        }
    }

    __syncthreads();   // feat + pf/mf visible to all waves

    // ======================== MLP loop ========================
    const int mt0 = 2 * w;   // this wave's layer1 global-mt base (hid 32w..32w+31)
    const f32x4 z = {0.0f, 0.0f, 0.0f, 0.0f};

    for (int m = 0; m < 4; ++m) {
        // ---------------- layer1: 2 mt x 4 pg ----------------
        f32x4 acc[2][4];
#pragma unroll
        for (int mtl = 0; mtl < 2; ++mtl)
#pragma unroll
            for (int pg = 0; pg < 4; ++pg) acc[mtl][pg] = z;

#pragma unroll
        for (int ks = 0; ks < 2; ++ks) {
            bf16x8 wh0, wl0, wh1, wl1;
            ldw(ws, m * 16 + (mt0 + 0) * 2 + ks, lane, wh0, wl0);
            ldw(ws, m * 16 + (mt0 + 1) * 2 + ks, lane, wh1, wl1);
            const int sb = ks ? ((m == 3) ? 64 : 32) : 0;
#pragma unroll
            for (int pg = 0; pg < 4; ++pg) {
                const int pp = pg * 16 + c;
                const bf16x8 bh = *reinterpret_cast<const bf16x8*>(&feat_h[pp * FSTR + sb + g * 8]);
                const bf16x8 bl = *reinterpret_cast<const bf16x8*>(&feat_l[pp * FSTR + sb + g * 8]);
                acc[0][pg] = MFMA16(wh0, bh, acc[0][pg]);
                acc[0][pg] = MFMA16(wh0, bl, acc[0][pg]);
                acc[0][pg] = MFMA16(wl0, bh, acc[0][pg]);
                acc[1][pg] = MFMA16(wh1, bh, acc[1][pg]);
                acc[1][pg] = MFMA16(wh1, bl, acc[1][pg]);
                acc[1][pg] = MFMA16(wl1, bh, acc[1][pg]);
            }
        }

        // relu + split + write h to LDS (rows hid0..hid0+3 contiguous)
#pragma unroll
        for (int mtl = 0; mtl < 2; ++mtl) {
            const int hid0 = (mt0 + mtl) * 16 + g * 4;
#pragma unroll
            for (int pg = 0; pg < 4; ++pg) {
                const int pp = pg * 16 + c;
                const float h0 = fmaxf(acc[mtl][pg][0], 0.0f);
                const float h1 = fmaxf(acc[mtl][pg][1], 0.0f);
                const float h2 = fmaxf(acc[mtl][pg][2], 0.0f);
                const float h3 = fmaxf(acc[mtl][pg][3], 0.0f);
                const unsigned short a0 = f2bf(h0), a1 = f2bf(h1), a2 = f2bf(h2), a3 = f2bf(h3);
                const unsigned short b0 = f2bf(h0 - bf2f(a0)), b1 = f2bf(h1 - bf2f(a1));
                const unsigned short b2_ = f2bf(h2 - bf2f(a2)), b3 = f2bf(h3 - bf2f(a3));
                *reinterpret_cast<uint2*>(&hb_h[pp * HSTR + hid0]) =
                    make_uint2((unsigned)a0 | ((unsigned)a1 << 16), (unsigned)a2 | ((unsigned)a3 << 16));
                *reinterpret_cast<uint2*>(&hb_l[pp * HSTR + hid0]) =
                    make_uint2((unsigned)b0 | ((unsigned)b1 << 16), (unsigned)b2_ | ((unsigned)b3 << 16));
            }
        }
        __syncthreads();   // h visible

        // ---------------- layer2: units (nt, point-half) ----------------
        int T, tb, obase, O; const float* b2;
        if (m == 0)      { T = 1; tb = 64; obase = 0;   O = 10; b2 = ob2; }
        else if (m == 1) { T = 2; tb = 68; obase = 10;  O = 30; b2 = cb2; }
        else if (m == 2) { T = 5; tb = 76; obase = 40;  O = 70; b2 = vb2; }
        else             { T = 3; tb = 96; obase = 110; O = 37; b2 = mb2; }

        f32x4 acc2[3][2];
        int nts[3], hfs[3]; bool actv[3];
#pragma unroll
        for (int s = 0; s < 3; ++s) {
            const int u = w + s * 4;
            actv[s] = (u < 2 * T);
            nts[s] = u >> 1; hfs[s] = u & 1;
#pragma unroll
            for (int p2 = 0; p2 < 2; ++p2) acc2[s][p2] = z;
        }
#pragma unroll
        for (int s = 0; s < 3; ++s) {
            if (actv[s]) {
#pragma unroll
                for (int ks = 0; ks < 4; ++ks) {
                    bf16x8 wh, wl;
                    ldw(ws, tb + nts[s] * 4 + ks, lane, wh, wl);
#pragma unroll
                    for (int p2 = 0; p2 < 2; ++p2) {
                        const int pp = hfs[s] * 32 + p2 * 16 + c;
                        const bf16x8 bh = *reinterpret_cast<const bf16x8*>(&hb_h[pp * HSTR + ks * 32 + g * 8]);
                        const bf16x8 bl = *reinterpret_cast<const bf16x8*>(&hb_l[pp * HSTR + ks * 32 + g * 8]);
                        acc2[s][p2] = MFMA16(wh, bh, acc2[s][p2]);
                        acc2[s][p2] = MFMA16(wh, bl, acc2[s][p2]);
                        acc2[s][p2] = MFMA16(wl, bh, acc2[s][p2]);
                    }
                }
            }
        }
        // epilogue: bias + activation + guarded store
#pragma unroll
        for (int s = 0; s < 3; ++s) {
            if (actv[s]) {
                const int o0 = nts[s] * 16 + g * 4;
#pragma unroll
                for (int p2 = 0; p2 < 2; ++p2) {
                    const int pp = hfs[s] * 32 + p2 * 16 + c;
                    const int pt = blockIdx.x * 64 + pp;
                    const float pfv = pfbuf[pp], mfv = mfbuf[pp];
                    if (pt < M) {
                        float* po = out + (size_t)pt * 160 + obase;
#pragma unroll
                        for (int r = 0; r < 4; ++r) {
                            const int o = o0 + r;
                            if (o < O) {
                                float v = acc2[s][p2][r] + b2[o];
                                if (m == 0)      v = fmaf(2.0f, sigf(2.0f * v), -1.0f) * pfv;
                                else if (m == 1) v = sigf(v);
                                else if (m == 3) v = v * mfv;
                                po[o] = v;
                            }
                        }
                    }
                }
            }
        }
        __syncthreads();   // layer2 reads done before next MLP overwrites h
    }
}

extern "C" void kernel_launch(void* const* d_in, const int* in_sizes, int n_in,
                              void* d_out, int out_size, void* d_ws, size_t ws_size,
                              hipStream_t stream) {
    const float* anchor_features = (const float*)d_in[0];
    const float* anchors         = (const float*)d_in[1];
    const float* scales          = (const float*)d_in[2];
    const float* time_features   = (const float*)d_in[3];
    const float* factors         = (const float*)d_in[4];
    const float* camtoworlds     = (const float*)d_in[5];
    const float* time_val        = (const float*)d_in[6];
    const float* ow1 = (const float*)d_in[7];
    const float* ob1 = (const float*)d_in[8];
    const float* ow2 = (const float*)d_in[9];
    const float* ob2 = (const float*)d_in[10];
    const float* cw1 = (const float*)d_in[11];
    const float* cb1 = (const float*)d_in[12];
    const float* cw2 = (const float*)d_in[13];
    const float* cb2 = (const float*)d_in[14];
    const float* vw1 = (const float*)d_in[15];
    const float* vb1 = (const float*)d_in[16];
    const float* vw2 = (const float*)d_in[17];
    const float* vb2 = (const float*)d_in[18];
    const float* mw1 = (const float*)d_in[19];
    const float* mb1 = (const float*)d_in[20];
    const float* mw2 = (const float*)d_in[21];
    const float* mb2 = (const float*)d_in[22];
    const int* visible_idx = (const int*)d_in[23];

    const int M = in_sizes[23];
    float* out = (float*)d_out;
    char* ws = (char*)d_ws;

    // 108 tiles x 2 KiB = 216 KiB pre-swizzled bf16 hi/lo weight fragments
    hipLaunchKernelGGL(prep_weights, dim3(108), dim3(64), 0, stream,
                       ow1, cw1, vw1, mw1, ob1, cb1, vb1, mb1,
                       ow2, cw2, vw2, mw2, ws);

    const int grid = (M + 63) / 64;   // 64 points per 256-thread block
    hipLaunchKernelGGL(gif_mfma_kernel, dim3(grid), dim3(256), 0, stream,
                       anchor_features, anchors, scales, time_features,
                       factors, camtoworlds, time_val, visible_idx,
                       ob2, cb2, vb2, mb2, ws, out, M);
}